// Round 14
// baseline (319.839 us; speedup 1.0000x reference)
//
#include <hip/hip_runtime.h>
#include <math.h>

#define N_NODES 100000
#define N_EDGES 1600000
#define F_IN    16
#define H_DIM   32
#define B_GRAPHS 256

#define BSHIFT  7
#define BSIZE   128                                   // nodes per bucket
#define NBUCKET ((N_NODES + BSIZE - 1) / BSIZE)       // 782
#define EPB     8192                                  // edges per chunk block
#define NCHUNK  ((N_EDGES + EPB - 1) / EPB)           // 196
#define CAPB    2560                                  // fixed bucket stride (mean 2048, +11 sigma)
#define CSTRIDE 2944                                  // csr entries reserved per bucket
#define TPAD    (NBUCKET * CSTRIDE)
#define CURSTR  16                                    // bucket_cur stride: 1 counter / 64B line
#define NPB     16                                    // nodes per layer block
#define LAYER_BLOCKS (N_NODES / NPB)                  // 6250

typedef int v4i __attribute__((ext_vector_type(4))); // nontemporal-load-able int4

// ---------------------------------------------------------------------------
__device__ inline float bf_lo(unsigned u) { return __uint_as_float(u << 16); }
__device__ inline float bf_hi(unsigned u) { return __uint_as_float(u & 0xffff0000u); }
__device__ inline unsigned pack_bf16x2(float a, float b) {
    unsigned ua = __float_as_uint(a), ub = __float_as_uint(b);
    ua += 0x7fffu + ((ua >> 16) & 1u);    // RNE
    ub += 0x7fffu + ((ub >> 16) & 1u);
    return (ua >> 16) | (ub & 0xffff0000u);
}

// fp8 e4m3 via exponent rebias (bias 7 -> 127, scale 2^±120). |v|<1 post-tanh
// => no saturation path needed beyond clamp.
__device__ inline unsigned f32_to_fp8(float v) {
    unsigned u = __float_as_uint(v * 0x1.0p-120f);
    unsigned s = (u >> 24) & 0x80u;
    u &= 0x7FFFFFFFu;
    u += 0x7FFFFu + ((u >> 20) & 1u);     // RNE at bit 20
    unsigned em = u >> 20;
    if (em > 0x7Eu) em = 0x7Eu;
    return s | em;
}
__device__ inline float fp8_to_f32(unsigned b) {
    unsigned s  = (b & 0x80u) << 24;
    unsigned em = (b & 0x7Fu) << 20;
    return __uint_as_float(s | em) * 0x1.0p120f;
}

// ---------------------------------------------------------------------------
__global__ __launch_bounds__(256) void init_cur_kernel(int* __restrict__ bucket_cur) {
    int b = blockIdx.x * 256 + threadIdx.x;
    if (b < NBUCKET) bucket_cur[b * CURSTR] = b * CAPB;
}

// Pass B: per-block histogram -> claim per-bucket runs (line-isolated
// counters) -> direct scattered writes. Record = src | dst_local<<20.
__global__ __launch_bounds__(1024) void passB_kernel(const int* __restrict__ ei,
                                                     int* __restrict__ bucket_cur,
                                                     unsigned* __restrict__ rec_out) {
    __shared__ int hist[NBUCKET];
    __shared__ int gcur[NBUCKET];
    int t = threadIdx.x;
    for (int k = t; k < NBUCKET; k += 1024) hist[k] = 0;
    __syncthreads();

    const int* dst = ei + N_EDGES;
    int base = blockIdx.x * EPB;
    int end  = base + EPB; if (end > N_EDGES) end = N_EDGES;

    for (int e = base + t; e < end; e += 1024) atomicAdd(&hist[dst[e] >> BSHIFT], 1);
    __syncthreads();

    for (int k = t; k < NBUCKET; k += 1024) {
        int h = hist[k];
        gcur[k] = h ? atomicAdd(&bucket_cur[k * CURSTR], h) : 0;
    }
    __syncthreads();

    for (int e = base + t; e < end; e += 1024) {
        int d = dst[e], s = ei[e];
        int bk = d >> BSHIFT;
        int pos = atomicAdd(&gcur[bk], 1);
        rec_out[pos] = (unsigned)s | ((unsigned)(d & (BSIZE - 1)) << 20);
    }
}

// Per-bucket in-degree -> dinv
__global__ __launch_bounds__(256) void dinv_kernel(const unsigned* __restrict__ rec,
                                                   const int* __restrict__ bucket_cur,
                                                   float* __restrict__ dinv) {
    __shared__ int cnt[BSIZE];
    int t = threadIdx.x, b = blockIdx.x;
    if (t < BSIZE) cnt[t] = 0;
    __syncthreads();
    int e1 = bucket_cur[b * CURSTR];
    for (int e = b * CAPB + t; e < e1; e += 256) atomicAdd(&cnt[rec[e] >> 20], 1);
    __syncthreads();
    int nd = (b << BSHIFT) + t;
    if (t < BSIZE && nd < N_NODES) dinv[nd] = rsqrtf((float)cnt[t] + 1.0f);
}

// Pass C: per-bucket node sort into padded interleaved CSR: entry=(src,coef).
// Rows padded to multiples of 4; dummy entries use the row's OWN node as src
// (coef=0). row_meta=(start,padded_len).
__global__ __launch_bounds__(256) void passC_kernel(const unsigned* __restrict__ rec,
                                                    const int* __restrict__ bucket_cur,
                                                    const float* __restrict__ dinv,
                                                    int2* __restrict__ row_meta,
                                                    int2* __restrict__ csr) {
    __shared__ unsigned stage[CAPB];
    __shared__ int cnt[BSIZE];
    __shared__ int pds[BSIZE];
    __shared__ int cur[BSIZE];
    __shared__ float sdv[BSIZE];
    int t = threadIdx.x, b = blockIdx.x;
    int node0 = b << BSHIFT;
    int e0 = b * CAPB;
    int n = bucket_cur[b * CURSTR] - e0;
    int pbase = b * CSTRIDE;              // 8-aligned
    if (t < BSIZE) {
        cnt[t] = 0;
        int nd = node0 + t;
        sdv[t] = (nd < N_NODES) ? dinv[nd] : 0.f;
    }
    __syncthreads();
    for (int k = t; k < n; k += 256) {
        unsigned r = rec[e0 + k];
        stage[k] = r;
        atomicAdd(&cnt[r >> 20], 1);
    }
    __syncthreads();
    int pd = 0;
    if (t < BSIZE) { pd = (cnt[t] + 3) & ~3; pds[t] = pd; }
    __syncthreads();
    for (int off = 1; off < BSIZE; off <<= 1) {
        int v = (t < BSIZE && t >= off) ? pds[t - off] : 0;
        __syncthreads();
        if (t < BSIZE) pds[t] += v;
        __syncthreads();
    }
    if (t < BSIZE) {
        int startp = pbase + pds[t] - pd;
        cur[t] = startp;
        int nd = node0 + t;
        if (nd < N_NODES) {
            row_meta[nd] = make_int2(startp, pd);
            for (int k = startp + cnt[t]; k < startp + pd; ++k)
                csr[k] = make_int2(nd, 0);   // dummy: own node, coef 0
        }
    }
    __syncthreads();
    for (int k = t; k < n; k += 256) {
        unsigned r = stage[k];
        int dl = r >> 20;
        int s  = r & 0xFFFFF;
        int pos = atomicAdd(&cur[dl], 1);
        csr[pos] = make_int2(s, __float_as_int(dinv[s] * sdv[dl]));
    }
}

// ---------------------------------------------------------------------------
// GCN layer. PACKED: h_in is fp8 rows (32 x 1B = 32B/row, L2-resident 3.2MB);
// else f32 x rows. CSR streamed with nontemporal loads (protects h in L2).
// 16-edge main chunks + 8/4 tails. Outputs fp8 (out8) and/or bf16x2 (outbf).
template <int FIN, bool PACKED>
__global__ __launch_bounds__(256) void layer_kernel(
        const void* __restrict__ h_in_v,
        const int2* __restrict__ row_meta,
        const v4i* __restrict__ csr4,      // 2 edges per v4i
        const float* __restrict__ dinv,
        const float* __restrict__ W,       // [FIN][32]
        const float* __restrict__ bias,    // [32]
        unsigned short* __restrict__ out8, // fp8x2 per lane, may be null
        unsigned* __restrict__ outbf) {    // bf16x2 per lane, may be null
    constexpr int STR = FIN + 1;
    __shared__ float sW[FIN * H_DIM];
    __shared__ float sb[H_DIM];
    __shared__ float agg[NPB][STR];
    int t = threadIdx.x;
    for (int k = t; k < FIN * H_DIM; k += 256) sW[k] = W[k];
    if (t < H_DIM) sb[t] = bias[t];

    int nl = t >> 4, ln = t & 15;
    int i = blockIdx.x * NPB + nl;
    int2 m = row_meta[i];
    float di = dinv[i], di2 = di * di;
    int q    = m.x >> 1;                // v4i index of row start (16B-aligned)
    int qend = (m.x + m.y) >> 1;

    if (PACKED) {
        const unsigned short* hp = (const unsigned short*)h_in_v;
        unsigned su = hp[i * 16 + ln];
        float acc0 = fp8_to_f32(su & 0xFF) * di2;
        float acc1 = fp8_to_f32(su >> 8) * di2;
        for (; q + 8 <= qend; q += 8) {     // 16 edges in flight
            v4i ca[8];
#pragma unroll
            for (int k = 0; k < 8; ++k) ca[k] = __builtin_nontemporal_load(&csr4[q + k]);
            unsigned v[16];
#pragma unroll
            for (int k = 0; k < 8; ++k) {
                v[2 * k]     = hp[ca[k].x * 16 + ln];
                v[2 * k + 1] = hp[ca[k].z * 16 + ln];
            }
#pragma unroll
            for (int k = 0; k < 8; ++k) {
                float c0 = __int_as_float(ca[k].y), c1 = __int_as_float(ca[k].w);
                unsigned u0 = v[2 * k], u1 = v[2 * k + 1];
                acc0 += fp8_to_f32(u0 & 0xFF) * c0 + fp8_to_f32(u1 & 0xFF) * c1;
                acc1 += fp8_to_f32(u0 >> 8)   * c0 + fp8_to_f32(u1 >> 8)   * c1;
            }
        }
        if (q + 4 <= qend) {                // 8-edge tail
            v4i ca[4];
#pragma unroll
            for (int k = 0; k < 4; ++k) ca[k] = __builtin_nontemporal_load(&csr4[q + k]);
#pragma unroll
            for (int k = 0; k < 4; ++k) {
                unsigned u0 = hp[ca[k].x * 16 + ln], u1 = hp[ca[k].z * 16 + ln];
                float c0 = __int_as_float(ca[k].y), c1 = __int_as_float(ca[k].w);
                acc0 += fp8_to_f32(u0 & 0xFF) * c0 + fp8_to_f32(u1 & 0xFF) * c1;
                acc1 += fp8_to_f32(u0 >> 8)   * c0 + fp8_to_f32(u1 >> 8)   * c1;
            }
            q += 4;
        }
        if (q < qend) {                     // 4-edge tail (2 v4is)
            v4i a = __builtin_nontemporal_load(&csr4[q]);
            v4i b = __builtin_nontemporal_load(&csr4[q + 1]);
            unsigned u0 = hp[a.x * 16 + ln], u1 = hp[a.z * 16 + ln];
            unsigned u2 = hp[b.x * 16 + ln], u3 = hp[b.z * 16 + ln];
            float c0 = __int_as_float(a.y), c1 = __int_as_float(a.w);
            float c2 = __int_as_float(b.y), c3 = __int_as_float(b.w);
            acc0 += fp8_to_f32(u0 & 0xFF) * c0 + fp8_to_f32(u1 & 0xFF) * c1
                  + fp8_to_f32(u2 & 0xFF) * c2 + fp8_to_f32(u3 & 0xFF) * c3;
            acc1 += fp8_to_f32(u0 >> 8) * c0 + fp8_to_f32(u1 >> 8) * c1
                  + fp8_to_f32(u2 >> 8) * c2 + fp8_to_f32(u3 >> 8) * c3;
        }
        agg[nl][2 * ln]     = acc0;
        agg[nl][2 * ln + 1] = acc1;
    } else {
        const float* xf = (const float*)h_in_v;
        float acc = xf[i * F_IN + ln] * di2;
        for (; q + 8 <= qend; q += 8) {
            v4i ca[8];
#pragma unroll
            for (int k = 0; k < 8; ++k) ca[k] = __builtin_nontemporal_load(&csr4[q + k]);
            float v[16];
#pragma unroll
            for (int k = 0; k < 8; ++k) {
                v[2 * k]     = xf[ca[k].x * F_IN + ln];
                v[2 * k + 1] = xf[ca[k].z * F_IN + ln];
            }
#pragma unroll
            for (int k = 0; k < 8; ++k)
                acc += v[2 * k] * __int_as_float(ca[k].y)
                     + v[2 * k + 1] * __int_as_float(ca[k].w);
        }
        if (q + 4 <= qend) {
            v4i ca[4];
#pragma unroll
            for (int k = 0; k < 4; ++k) ca[k] = __builtin_nontemporal_load(&csr4[q + k]);
#pragma unroll
            for (int k = 0; k < 4; ++k)
                acc += xf[ca[k].x * F_IN + ln] * __int_as_float(ca[k].y)
                     + xf[ca[k].z * F_IN + ln] * __int_as_float(ca[k].w);
            q += 4;
        }
        if (q < qend) {
            v4i a = __builtin_nontemporal_load(&csr4[q]);
            v4i b = __builtin_nontemporal_load(&csr4[q + 1]);
            acc += xf[a.x * F_IN + ln] * __int_as_float(a.y)
                 + xf[a.z * F_IN + ln] * __int_as_float(a.w)
                 + xf[b.x * F_IN + ln] * __int_as_float(b.y)
                 + xf[b.z * F_IN + ln] * __int_as_float(b.w);
        }
        agg[nl][ln] = acc;
    }
    __syncthreads();

    // transform + bias + tanh + store (16 nodes x 16 feat-pairs)
    int j0 = 2 * ln;
    float o0 = sb[j0], o1 = sb[j0 + 1];
    const float* arow = &agg[nl][0];
#pragma unroll
    for (int k = 0; k < FIN; ++k) {
        float a = arow[k];
        o0 += a * sW[k * H_DIM + j0];
        o1 += a * sW[k * H_DIM + j0 + 1];
    }
    o0 = tanhf(o0); o1 = tanhf(o1);
    if (out8)  out8[i * 16 + ln]  = (unsigned short)(f32_to_fp8(o0) | (f32_to_fp8(o1) << 8));
    if (outbf) outbf[i * 16 + ln] = pack_bf16x2(o0, o1);
}

// ---------------------------------------------------------------------------
// Per-graph pooling (batch sorted) + linear head, reading packed bf16 h.
__global__ __launch_bounds__(256) void pool_kernel(const unsigned* __restrict__ hp,
                                                   const int* __restrict__ batch,
                                                   const float* __restrict__ Wout,
                                                   const float* __restrict__ bout,
                                                   float* __restrict__ out) {
    int b = blockIdx.x;
    int t = threadIdx.x;
    int lane_n = t >> 5;
    int j = t & 31;

    int lo = 0, hi = N_NODES;
    while (lo < hi) { int mid = (lo + hi) >> 1; if (batch[mid] < b) lo = mid + 1; else hi = mid; }
    int start = lo;
    hi = N_NODES;
    while (lo < hi) { int mid = (lo + hi) >> 1; if (batch[mid] < b + 1) lo = mid + 1; else hi = mid; }
    int end = lo;

    float vmax = -INFINITY, vsum = 0.f;
    for (int i = start + lane_n; i < end; i += 8) {
        unsigned q = hp[i * 16 + (j >> 1)];
        float v = (j & 1) ? bf_hi(q) : bf_lo(q);
        vmax = fmaxf(vmax, v);
        vsum += v;
    }

    __shared__ float smax[8][32];
    __shared__ float ssum[8][32];
    __shared__ float pool96[96];
    smax[lane_n][j] = vmax;
    ssum[lane_n][j] = vsum;
    __syncthreads();

    if (t < 32) {
        float m = smax[0][t], s = ssum[0][t];
#pragma unroll
        for (int n = 1; n < 8; ++n) { m = fmaxf(m, smax[n][t]); s += ssum[n][t]; }
        int cnt = end - start;
        float mean = s / fmaxf((float)cnt, 1.0f);
        pool96[t]      = m;
        pool96[32 + t] = mean;
        pool96[64 + t] = s;
    }
    __syncthreads();

    if (t < 96) out[B_GRAPHS + b * 96 + t] = pool96[t];

    __shared__ float dotbuf[96];
    if (t < 96) dotbuf[t] = pool96[t] * Wout[t];
    __syncthreads();
    if (t == 0) {
        float acc = 0.f;
#pragma unroll
        for (int k = 0; k < 96; ++k) acc += dotbuf[k];
        out[b] = acc + bout[0];
    }
}

// ---------------------------------------------------------------------------
extern "C" void kernel_launch(void* const* d_in, const int* in_sizes, int n_in,
                              void* d_out, int out_size, void* d_ws, size_t ws_size,
                              hipStream_t stream) {
    const float* x     = (const float*)d_in[0];
    const int*   ei    = (const int*)  d_in[1];   // src = ei[0:E], dst = ei[E:2E]
    const int*   batch = (const int*)  d_in[2];
    const float* W0    = (const float*)d_in[3];
    const float* b0    = (const float*)d_in[4];
    const float* W1    = (const float*)d_in[5];
    const float* b1    = (const float*)d_in[6];
    const float* W2    = (const float*)d_in[7];
    const float* b2    = (const float*)d_in[8];
    const float* W3    = (const float*)d_in[9];
    const float* b3    = (const float*)d_in[10];
    const float* Wout  = (const float*)d_in[11];
    const float* bout  = (const float*)d_in[12];
    float* out = (float*)d_out;

    char* p = (char*)d_ws;
    float*          dinv       = (float*)p;          p += (size_t)N_NODES * 4;
    unsigned short* h8A        = (unsigned short*)p; p += (size_t)N_NODES * 16 * 2;   // 3.2 MB
    unsigned short* h8B        = (unsigned short*)p; p += (size_t)N_NODES * 16 * 2;   // 3.2 MB
    unsigned*       rec        = (unsigned*)p;       p += (size_t)NBUCKET * CAPB * 4; // 8 MB, reused
    int2*           csr        = (int2*)p;           p += (size_t)TPAD * 8;           // 18.4 MB
    int2*           row_meta   = (int2*)p;           p += (size_t)N_NODES * 8;
    int*            bucket_cur = (int*)p;            p += (size_t)NBUCKET * CURSTR * 4;
    unsigned* hBF = rec;   // alias: rec dead once passC completes (bf16 h for pool)

    // ---- edge build: fixed-stride buckets -> per-bucket node sort -> CSR ----
    init_cur_kernel<<<(NBUCKET + 255) / 256, 256, 0, stream>>>(bucket_cur);
    passB_kernel<<<NCHUNK, 1024, 0, stream>>>(ei, bucket_cur, rec);
    dinv_kernel<<<NBUCKET, 256, 0, stream>>>(rec, bucket_cur, dinv);
    passC_kernel<<<NBUCKET, 256, 0, stream>>>(rec, bucket_cur, dinv, row_meta, csr);

    // ---- 4 GCN layers: fp8 intermediate h (3.2MB, L2-resident), nt CSR ----
    layer_kernel<F_IN, false><<<LAYER_BLOCKS, 256, 0, stream>>>(
        x,   row_meta, (const v4i*)csr, dinv, W0, b0, h8A, (unsigned*)nullptr);
    layer_kernel<H_DIM, true><<<LAYER_BLOCKS, 256, 0, stream>>>(
        h8A, row_meta, (const v4i*)csr, dinv, W1, b1, h8B, (unsigned*)nullptr);
    layer_kernel<H_DIM, true><<<LAYER_BLOCKS, 256, 0, stream>>>(
        h8B, row_meta, (const v4i*)csr, dinv, W2, b2, h8A, (unsigned*)nullptr);
    layer_kernel<H_DIM, true><<<LAYER_BLOCKS, 256, 0, stream>>>(
        h8A, row_meta, (const v4i*)csr, dinv, W3, b3, (unsigned short*)nullptr, hBF);

    pool_kernel<<<B_GRAPHS, 256, 0, stream>>>(hBF, batch, Wout, bout, out);
}

// Round 15
// 307.860 us; speedup vs baseline: 1.0389x; 1.0389x over previous
//
#include <hip/hip_runtime.h>
#include <math.h>

#define N_NODES 100000
#define N_EDGES 1600000
#define F_IN    16
#define H_DIM   32
#define B_GRAPHS 256

#define BSHIFT  7
#define BSIZE   128                                   // nodes per bucket
#define NBUCKET ((N_NODES + BSIZE - 1) / BSIZE)       // 782
#define EPB     8192                                  // edges per chunk block
#define NCHUNK  ((N_EDGES + EPB - 1) / EPB)           // 196
#define CAPB    2560                                  // fixed bucket stride (mean 2048, +11 sigma)
#define CSTRIDE 2944                                  // csr entries reserved per bucket
#define TPAD    (NBUCKET * CSTRIDE)
#define CURSTR  16                                    // bucket_cur stride: 1 counter / 64B line
#define NPB     16                                    // nodes per layer block
#define LAYER_BLOCKS (N_NODES / NPB)                  // 6250

typedef int   v4i __attribute__((ext_vector_type(4)));
typedef float v2f __attribute__((ext_vector_type(2)));

#if defined(__has_builtin)
#if __has_builtin(__builtin_amdgcn_cvt_pk_f32_fp8) && __has_builtin(__builtin_amdgcn_cvt_pk_fp8_f32)
#define HW_FP8 1
#endif
#endif

// ---------------------------------------------------------------------------
__device__ inline float bf_lo(unsigned u) { return __uint_as_float(u << 16); }
__device__ inline float bf_hi(unsigned u) { return __uint_as_float(u & 0xffff0000u); }
__device__ inline unsigned pack_bf16x2(float a, float b) {
    unsigned ua = __float_as_uint(a), ub = __float_as_uint(b);
    ua += 0x7fffu + ((ua >> 16) & 1u);    // RNE
    ub += 0x7fffu + ((ub >> 16) & 1u);
    return (ua >> 16) | (ub & 0xffff0000u);
}

// software fp8 fallback (e4m3 via exponent rebias; consistent encode/decode)
__device__ inline unsigned sw_f32_to_fp8(float v) {
    unsigned u = __float_as_uint(v * 0x1.0p-120f);
    unsigned s = (u >> 24) & 0x80u;
    u &= 0x7FFFFFFFu;
    u += 0x7FFFFu + ((u >> 20) & 1u);
    unsigned em = u >> 20;
    if (em > 0x7Eu) em = 0x7Eu;
    return s | em;
}
__device__ inline float sw_fp8_to_f32(unsigned b) {
    unsigned s  = (b & 0x80u) << 24;
    unsigned em = (b & 0x7Fu) << 20;
    return __uint_as_float(s | em) * 0x1.0p120f;
}

// fp8x2 <-> f32x2, hardware v_cvt when available (1 instruction each way)
__device__ inline v2f fp8x2_to_f32x2(unsigned u) {
#ifdef HW_FP8
    return __builtin_amdgcn_cvt_pk_f32_fp8(u & 0xFFFFu, false);
#else
    v2f r; r.x = sw_fp8_to_f32(u & 0xFF); r.y = sw_fp8_to_f32((u >> 8) & 0xFF); return r;
#endif
}
__device__ inline unsigned short f32x2_to_fp8x2(float a, float b) {
#ifdef HW_FP8
    return (unsigned short)__builtin_amdgcn_cvt_pk_fp8_f32(a, b, 0, false);
#else
    return (unsigned short)(sw_f32_to_fp8(a) | (sw_f32_to_fp8(b) << 8));
#endif
}

// ---------------------------------------------------------------------------
__global__ __launch_bounds__(256) void init_cur_kernel(int* __restrict__ bucket_cur) {
    int b = blockIdx.x * 256 + threadIdx.x;
    if (b < NBUCKET) bucket_cur[b * CURSTR] = b * CAPB;
}

// Pass B: per-block histogram -> claim per-bucket runs (line-isolated
// counters) -> direct scattered writes. Record = src | dst_local<<20.
__global__ __launch_bounds__(1024) void passB_kernel(const int* __restrict__ ei,
                                                     int* __restrict__ bucket_cur,
                                                     unsigned* __restrict__ rec_out) {
    __shared__ int hist[NBUCKET];
    __shared__ int gcur[NBUCKET];
    int t = threadIdx.x;
    for (int k = t; k < NBUCKET; k += 1024) hist[k] = 0;
    __syncthreads();

    const int* dst = ei + N_EDGES;
    int base = blockIdx.x * EPB;
    int end  = base + EPB; if (end > N_EDGES) end = N_EDGES;

    for (int e = base + t; e < end; e += 1024) atomicAdd(&hist[dst[e] >> BSHIFT], 1);
    __syncthreads();

    for (int k = t; k < NBUCKET; k += 1024) {
        int h = hist[k];
        gcur[k] = h ? atomicAdd(&bucket_cur[k * CURSTR], h) : 0;
    }
    __syncthreads();

    for (int e = base + t; e < end; e += 1024) {
        int d = dst[e], s = ei[e];
        int bk = d >> BSHIFT;
        int pos = atomicAdd(&gcur[bk], 1);
        rec_out[pos] = (unsigned)s | ((unsigned)(d & (BSIZE - 1)) << 20);
    }
}

// Per-bucket in-degree -> dinv
__global__ __launch_bounds__(256) void dinv_kernel(const unsigned* __restrict__ rec,
                                                   const int* __restrict__ bucket_cur,
                                                   float* __restrict__ dinv) {
    __shared__ int cnt[BSIZE];
    int t = threadIdx.x, b = blockIdx.x;
    if (t < BSIZE) cnt[t] = 0;
    __syncthreads();
    int e1 = bucket_cur[b * CURSTR];
    for (int e = b * CAPB + t; e < e1; e += 256) atomicAdd(&cnt[rec[e] >> 20], 1);
    __syncthreads();
    int nd = (b << BSHIFT) + t;
    if (t < BSIZE && nd < N_NODES) dinv[nd] = rsqrtf((float)cnt[t] + 1.0f);
}

// Pass C: per-bucket node sort into padded interleaved CSR: entry=(src,coef).
// Rows padded to multiples of 4; dummy entries use the row's OWN node as src
// (coef=0). row_meta=(start,padded_len).
__global__ __launch_bounds__(256) void passC_kernel(const unsigned* __restrict__ rec,
                                                    const int* __restrict__ bucket_cur,
                                                    const float* __restrict__ dinv,
                                                    int2* __restrict__ row_meta,
                                                    int2* __restrict__ csr) {
    __shared__ unsigned stage[CAPB];
    __shared__ int cnt[BSIZE];
    __shared__ int pds[BSIZE];
    __shared__ int cur[BSIZE];
    __shared__ float sdv[BSIZE];
    int t = threadIdx.x, b = blockIdx.x;
    int node0 = b << BSHIFT;
    int e0 = b * CAPB;
    int n = bucket_cur[b * CURSTR] - e0;
    int pbase = b * CSTRIDE;              // 8-aligned
    if (t < BSIZE) {
        cnt[t] = 0;
        int nd = node0 + t;
        sdv[t] = (nd < N_NODES) ? dinv[nd] : 0.f;
    }
    __syncthreads();
    for (int k = t; k < n; k += 256) {
        unsigned r = rec[e0 + k];
        stage[k] = r;
        atomicAdd(&cnt[r >> 20], 1);
    }
    __syncthreads();
    int pd = 0;
    if (t < BSIZE) { pd = (cnt[t] + 3) & ~3; pds[t] = pd; }
    __syncthreads();
    for (int off = 1; off < BSIZE; off <<= 1) {
        int v = (t < BSIZE && t >= off) ? pds[t - off] : 0;
        __syncthreads();
        if (t < BSIZE) pds[t] += v;
        __syncthreads();
    }
    if (t < BSIZE) {
        int startp = pbase + pds[t] - pd;
        cur[t] = startp;
        int nd = node0 + t;
        if (nd < N_NODES) {
            row_meta[nd] = make_int2(startp, pd);
            for (int k = startp + cnt[t]; k < startp + pd; ++k)
                csr[k] = make_int2(nd, 0);   // dummy: own node, coef 0
        }
    }
    __syncthreads();
    for (int k = t; k < n; k += 256) {
        unsigned r = stage[k];
        int dl = r >> 20;
        int s  = r & 0xFFFFF;
        int pos = atomicAdd(&cur[dl], 1);
        csr[pos] = make_int2(s, __float_as_int(dinv[s] * sdv[dl]));
    }
}

// ---------------------------------------------------------------------------
// GCN layer. PACKED: h_in is fp8 rows (32B/row, 3.2MB L2-resident), HW cvt
// decode; else f32 x rows. CSR streamed nontemporal. 16-edge chunks + tails.
template <int FIN, bool PACKED>
__global__ __launch_bounds__(256) void layer_kernel(
        const void* __restrict__ h_in_v,
        const int2* __restrict__ row_meta,
        const v4i* __restrict__ csr4,      // 2 edges per v4i
        const float* __restrict__ dinv,
        const float* __restrict__ W,       // [FIN][32]
        const float* __restrict__ bias,    // [32]
        unsigned short* __restrict__ out8, // fp8x2 per lane, may be null
        unsigned* __restrict__ outbf) {    // bf16x2 per lane, may be null
    constexpr int STR = FIN + 1;
    __shared__ float sW[FIN * H_DIM];
    __shared__ float sb[H_DIM];
    __shared__ float agg[NPB][STR];
    int t = threadIdx.x;
    for (int k = t; k < FIN * H_DIM; k += 256) sW[k] = W[k];
    if (t < H_DIM) sb[t] = bias[t];

    int nl = t >> 4, ln = t & 15;
    int i = blockIdx.x * NPB + nl;
    int2 m = row_meta[i];
    float di = dinv[i], di2 = di * di;
    int q    = m.x >> 1;                // v4i index of row start (16B-aligned)
    int qend = (m.x + m.y) >> 1;

    if (PACKED) {
        const unsigned short* hp = (const unsigned short*)h_in_v;
        v2f sf = fp8x2_to_f32x2(hp[i * 16 + ln]);
        float acc0 = sf.x * di2, acc1 = sf.y * di2;
        for (; q + 8 <= qend; q += 8) {     // 16 edges in flight
            v4i ca[8];
#pragma unroll
            for (int k = 0; k < 8; ++k) ca[k] = __builtin_nontemporal_load(&csr4[q + k]);
            unsigned v[16];
#pragma unroll
            for (int k = 0; k < 8; ++k) {
                v[2 * k]     = hp[ca[k].x * 16 + ln];
                v[2 * k + 1] = hp[ca[k].z * 16 + ln];
            }
#pragma unroll
            for (int k = 0; k < 8; ++k) {
                float c0 = __int_as_float(ca[k].y), c1 = __int_as_float(ca[k].w);
                v2f f0 = fp8x2_to_f32x2(v[2 * k]);
                v2f f1 = fp8x2_to_f32x2(v[2 * k + 1]);
                acc0 += f0.x * c0 + f1.x * c1;
                acc1 += f0.y * c0 + f1.y * c1;
            }
        }
        if (q + 4 <= qend) {                // 8-edge tail
            v4i ca[4];
#pragma unroll
            for (int k = 0; k < 4; ++k) ca[k] = __builtin_nontemporal_load(&csr4[q + k]);
#pragma unroll
            for (int k = 0; k < 4; ++k) {
                v2f f0 = fp8x2_to_f32x2(hp[ca[k].x * 16 + ln]);
                v2f f1 = fp8x2_to_f32x2(hp[ca[k].z * 16 + ln]);
                float c0 = __int_as_float(ca[k].y), c1 = __int_as_float(ca[k].w);
                acc0 += f0.x * c0 + f1.x * c1;
                acc1 += f0.y * c0 + f1.y * c1;
            }
            q += 4;
        }
        if (q < qend) {                     // 4-edge tail (2 v4is)
            v4i a = __builtin_nontemporal_load(&csr4[q]);
            v4i b = __builtin_nontemporal_load(&csr4[q + 1]);
            v2f f0 = fp8x2_to_f32x2(hp[a.x * 16 + ln]);
            v2f f1 = fp8x2_to_f32x2(hp[a.z * 16 + ln]);
            v2f f2 = fp8x2_to_f32x2(hp[b.x * 16 + ln]);
            v2f f3 = fp8x2_to_f32x2(hp[b.z * 16 + ln]);
            float c0 = __int_as_float(a.y), c1 = __int_as_float(a.w);
            float c2 = __int_as_float(b.y), c3 = __int_as_float(b.w);
            acc0 += f0.x * c0 + f1.x * c1 + f2.x * c2 + f3.x * c3;
            acc1 += f0.y * c0 + f1.y * c1 + f2.y * c2 + f3.y * c3;
        }
        agg[nl][2 * ln]     = acc0;
        agg[nl][2 * ln + 1] = acc1;
    } else {
        const float* xf = (const float*)h_in_v;
        float acc = xf[i * F_IN + ln] * di2;
        for (; q + 8 <= qend; q += 8) {
            v4i ca[8];
#pragma unroll
            for (int k = 0; k < 8; ++k) ca[k] = __builtin_nontemporal_load(&csr4[q + k]);
            float v[16];
#pragma unroll
            for (int k = 0; k < 8; ++k) {
                v[2 * k]     = xf[ca[k].x * F_IN + ln];
                v[2 * k + 1] = xf[ca[k].z * F_IN + ln];
            }
#pragma unroll
            for (int k = 0; k < 8; ++k)
                acc += v[2 * k] * __int_as_float(ca[k].y)
                     + v[2 * k + 1] * __int_as_float(ca[k].w);
        }
        if (q + 4 <= qend) {
            v4i ca[4];
#pragma unroll
            for (int k = 0; k < 4; ++k) ca[k] = __builtin_nontemporal_load(&csr4[q + k]);
#pragma unroll
            for (int k = 0; k < 4; ++k)
                acc += xf[ca[k].x * F_IN + ln] * __int_as_float(ca[k].y)
                     + xf[ca[k].z * F_IN + ln] * __int_as_float(ca[k].w);
            q += 4;
        }
        if (q < qend) {
            v4i a = __builtin_nontemporal_load(&csr4[q]);
            v4i b = __builtin_nontemporal_load(&csr4[q + 1]);
            acc += xf[a.x * F_IN + ln] * __int_as_float(a.y)
                 + xf[a.z * F_IN + ln] * __int_as_float(a.w)
                 + xf[b.x * F_IN + ln] * __int_as_float(b.y)
                 + xf[b.z * F_IN + ln] * __int_as_float(b.w);
        }
        agg[nl][ln] = acc;
    }
    __syncthreads();

    // transform + bias + tanh + store (16 nodes x 16 feat-pairs)
    int j0 = 2 * ln;
    float o0 = sb[j0], o1 = sb[j0 + 1];
    const float* arow = &agg[nl][0];
#pragma unroll
    for (int k = 0; k < FIN; ++k) {
        float a = arow[k];
        o0 += a * sW[k * H_DIM + j0];
        o1 += a * sW[k * H_DIM + j0 + 1];
    }
    o0 = tanhf(o0); o1 = tanhf(o1);
    if (out8)  out8[i * 16 + ln]  = f32x2_to_fp8x2(o0, o1);
    if (outbf) outbf[i * 16 + ln] = pack_bf16x2(o0, o1);
}

// ---------------------------------------------------------------------------
// Per-graph pooling (batch sorted) + linear head, reading packed bf16 h.
__global__ __launch_bounds__(256) void pool_kernel(const unsigned* __restrict__ hp,
                                                   const int* __restrict__ batch,
                                                   const float* __restrict__ Wout,
                                                   const float* __restrict__ bout,
                                                   float* __restrict__ out) {
    int b = blockIdx.x;
    int t = threadIdx.x;
    int lane_n = t >> 5;
    int j = t & 31;

    int lo = 0, hi = N_NODES;
    while (lo < hi) { int mid = (lo + hi) >> 1; if (batch[mid] < b) lo = mid + 1; else hi = mid; }
    int start = lo;
    hi = N_NODES;
    while (lo < hi) { int mid = (lo + hi) >> 1; if (batch[mid] < b + 1) lo = mid + 1; else hi = mid; }
    int end = lo;

    float vmax = -INFINITY, vsum = 0.f;
    for (int i = start + lane_n; i < end; i += 8) {
        unsigned q = hp[i * 16 + (j >> 1)];
        float v = (j & 1) ? bf_hi(q) : bf_lo(q);
        vmax = fmaxf(vmax, v);
        vsum += v;
    }

    __shared__ float smax[8][32];
    __shared__ float ssum[8][32];
    __shared__ float pool96[96];
    smax[lane_n][j] = vmax;
    ssum[lane_n][j] = vsum;
    __syncthreads();

    if (t < 32) {
        float m = smax[0][t], s = ssum[0][t];
#pragma unroll
        for (int n = 1; n < 8; ++n) { m = fmaxf(m, smax[n][t]); s += ssum[n][t]; }
        int cnt = end - start;
        float mean = s / fmaxf((float)cnt, 1.0f);
        pool96[t]      = m;
        pool96[32 + t] = mean;
        pool96[64 + t] = s;
    }
    __syncthreads();

    if (t < 96) out[B_GRAPHS + b * 96 + t] = pool96[t];

    __shared__ float dotbuf[96];
    if (t < 96) dotbuf[t] = pool96[t] * Wout[t];
    __syncthreads();
    if (t == 0) {
        float acc = 0.f;
#pragma unroll
        for (int k = 0; k < 96; ++k) acc += dotbuf[k];
        out[b] = acc + bout[0];
    }
}

// ---------------------------------------------------------------------------
extern "C" void kernel_launch(void* const* d_in, const int* in_sizes, int n_in,
                              void* d_out, int out_size, void* d_ws, size_t ws_size,
                              hipStream_t stream) {
    const float* x     = (const float*)d_in[0];
    const int*   ei    = (const int*)  d_in[1];   // src = ei[0:E], dst = ei[E:2E]
    const int*   batch = (const int*)  d_in[2];
    const float* W0    = (const float*)d_in[3];
    const float* b0    = (const float*)d_in[4];
    const float* W1    = (const float*)d_in[5];
    const float* b1    = (const float*)d_in[6];
    const float* W2    = (const float*)d_in[7];
    const float* b2    = (const float*)d_in[8];
    const float* W3    = (const float*)d_in[9];
    const float* b3    = (const float*)d_in[10];
    const float* Wout  = (const float*)d_in[11];
    const float* bout  = (const float*)d_in[12];
    float* out = (float*)d_out;

    char* p = (char*)d_ws;
    float*          dinv       = (float*)p;          p += (size_t)N_NODES * 4;
    unsigned short* h8A        = (unsigned short*)p; p += (size_t)N_NODES * 16 * 2;   // 3.2 MB
    unsigned short* h8B        = (unsigned short*)p; p += (size_t)N_NODES * 16 * 2;   // 3.2 MB
    unsigned*       rec        = (unsigned*)p;       p += (size_t)NBUCKET * CAPB * 4; // 8 MB, reused
    int2*           csr        = (int2*)p;           p += (size_t)TPAD * 8;           // 18.4 MB
    int2*           row_meta   = (int2*)p;           p += (size_t)N_NODES * 8;
    int*            bucket_cur = (int*)p;            p += (size_t)NBUCKET * CURSTR * 4;
    unsigned* hBF = rec;   // alias: rec dead once passC completes (bf16 h for pool)

    // ---- edge build: fixed-stride buckets -> per-bucket node sort -> CSR ----
    init_cur_kernel<<<(NBUCKET + 255) / 256, 256, 0, stream>>>(bucket_cur);
    passB_kernel<<<NCHUNK, 1024, 0, stream>>>(ei, bucket_cur, rec);
    dinv_kernel<<<NBUCKET, 256, 0, stream>>>(rec, bucket_cur, dinv);
    passC_kernel<<<NBUCKET, 256, 0, stream>>>(rec, bucket_cur, dinv, row_meta, csr);

    // ---- 4 GCN layers: fp8 h (L2-resident) with HW v_cvt decode/encode ----
    layer_kernel<F_IN, false><<<LAYER_BLOCKS, 256, 0, stream>>>(
        x,   row_meta, (const v4i*)csr, dinv, W0, b0, h8A, (unsigned*)nullptr);
    layer_kernel<H_DIM, true><<<LAYER_BLOCKS, 256, 0, stream>>>(
        h8A, row_meta, (const v4i*)csr, dinv, W1, b1, h8B, (unsigned*)nullptr);
    layer_kernel<H_DIM, true><<<LAYER_BLOCKS, 256, 0, stream>>>(
        h8B, row_meta, (const v4i*)csr, dinv, W2, b2, h8A, (unsigned*)nullptr);
    layer_kernel<H_DIM, true><<<LAYER_BLOCKS, 256, 0, stream>>>(
        h8A, row_meta, (const v4i*)csr, dinv, W3, b3, (unsigned short*)nullptr, hBF);

    pool_kernel<<<B_GRAPHS, 256, 0, stream>>>(hBF, batch, Wout, bout, out);
}

// Round 17
// 283.074 us; speedup vs baseline: 1.1299x; 1.0876x over previous
//
#include <hip/hip_runtime.h>
#include <math.h>

#define N_NODES 100000
#define N_EDGES 1600000
#define F_IN    16
#define H_DIM   32
#define B_GRAPHS 256

#define BSHIFT  7
#define BSIZE   128
#define NBUCKET ((N_NODES + BSIZE - 1) / BSIZE)       // 782
#define EPB     8192
#define NCHUNK  ((N_EDGES + EPB - 1) / EPB)           // 196
#define CAPB    2560                                  // raw bucket stride (mean 2048, +11 sigma)
#define CSTRIDE 3584                                  // csr entries/bucket (pad-16 rows)
#define TPAD    (NBUCKET * CSTRIDE)
#define CURSTR  16                                    // bucket_cur: 1 counter per 64B line
#define NPB0    16                                    // nodes/block, layer0 (16 lanes/row)
#define L0_BLOCKS (N_NODES / NPB0)                    // 6250
#define NPB8    32                                    // nodes/block, fp8 layers (8 lanes/row)
#define L8_BLOCKS (N_NODES / NPB8)                    // 3125

typedef int   v4i __attribute__((ext_vector_type(4)));
typedef float v2f __attribute__((ext_vector_type(2)));

#if defined(__has_builtin)
#if __has_builtin(__builtin_amdgcn_cvt_pk_f32_fp8) && __has_builtin(__builtin_amdgcn_cvt_pk_fp8_f32)
#define HW_FP8 1
#endif
#endif

// ---------------------------------------------------------------------------
__device__ inline unsigned pack_bf16x2(float a, float b) {
    unsigned ua = __float_as_uint(a), ub = __float_as_uint(b);
    ua += 0x7fffu + ((ua >> 16) & 1u);    // RNE
    ub += 0x7fffu + ((ub >> 16) & 1u);
    return (ua >> 16) | (ub & 0xffff0000u);
}
__device__ inline float bf_lo(unsigned u) { return __uint_as_float(u << 16); }
__device__ inline float bf_hi(unsigned u) { return __uint_as_float(u & 0xffff0000u); }

// software fp8 fallback (e4m3 rebias)
__device__ inline unsigned sw_f32_to_fp8(float v) {
    unsigned u = __float_as_uint(v * 0x1.0p-120f);
    unsigned s = (u >> 24) & 0x80u;
    u &= 0x7FFFFFFFu;
    u += 0x7FFFFu + ((u >> 20) & 1u);
    unsigned em = u >> 20;
    if (em > 0x7Eu) em = 0x7Eu;
    return s | em;
}
__device__ inline float sw_fp8_to_f32(unsigned b) {
    unsigned s  = (b & 0x80u) << 24;
    unsigned em = (b & 0x7Fu) << 20;
    return __uint_as_float(s | em) * 0x1.0p120f;
}
// decode selected 16-bit half of a dword (2 fp8) to 2 floats.
// HI selector is a template param: the builtin requires an immediate.
template <bool HI>
__device__ inline v2f fp8pk(unsigned u) {
#ifdef HW_FP8
    return __builtin_amdgcn_cvt_pk_f32_fp8((int)u, HI);
#else
    unsigned h = HI ? (u >> 16) : (u & 0xFFFFu);
    v2f r; r.x = sw_fp8_to_f32(h & 0xFF); r.y = sw_fp8_to_f32((h >> 8) & 0xFF); return r;
#endif
}
__device__ inline unsigned short f32x2_to_fp8x2(float a, float b) {
#ifdef HW_FP8
    return (unsigned short)__builtin_amdgcn_cvt_pk_fp8_f32(a, b, 0, false);
#else
    return (unsigned short)(sw_f32_to_fp8(a) | (sw_f32_to_fp8(b) << 8));
#endif
}

// ---------------------------------------------------------------------------
__global__ __launch_bounds__(256) void init_cur_kernel(int* __restrict__ bucket_cur) {
    int b = blockIdx.x * 256 + threadIdx.x;
    if (b < NBUCKET) bucket_cur[b * CURSTR] = b * CAPB;
}

// Pass B: per-block histogram -> claim per-bucket runs (line-isolated) ->
// direct scattered writes. Record = src | dst_local<<20.
__global__ __launch_bounds__(1024) void passB_kernel(const int* __restrict__ ei,
                                                     int* __restrict__ bucket_cur,
                                                     unsigned* __restrict__ rec_out) {
    __shared__ int hist[NBUCKET];
    __shared__ int gcur[NBUCKET];
    int t = threadIdx.x;
    for (int k = t; k < NBUCKET; k += 1024) hist[k] = 0;
    __syncthreads();

    const int* dst = ei + N_EDGES;
    int base = blockIdx.x * EPB;
    int end  = base + EPB; if (end > N_EDGES) end = N_EDGES;

    for (int e = base + t; e < end; e += 1024) atomicAdd(&hist[dst[e] >> BSHIFT], 1);
    __syncthreads();

    for (int k = t; k < NBUCKET; k += 1024) {
        int h = hist[k];
        gcur[k] = h ? atomicAdd(&bucket_cur[k * CURSTR], h) : 0;
    }
    __syncthreads();

    for (int e = base + t; e < end; e += 1024) {
        int d = dst[e], s = ei[e];
        int bk = d >> BSHIFT;
        int pos = atomicAdd(&gcur[bk], 1);
        rec_out[pos] = (unsigned)s | ((unsigned)(d & (BSIZE - 1)) << 20);
    }
}

// Per-bucket in-degree -> dinv
__global__ __launch_bounds__(256) void dinv_kernel(const unsigned* __restrict__ rec,
                                                   const int* __restrict__ bucket_cur,
                                                   float* __restrict__ dinv) {
    __shared__ int cnt[BSIZE];
    int t = threadIdx.x, b = blockIdx.x;
    if (t < BSIZE) cnt[t] = 0;
    __syncthreads();
    int e1 = bucket_cur[b * CURSTR];
    for (int e = b * CAPB + t; e < e1; e += 256) atomicAdd(&cnt[rec[e] >> 20], 1);
    __syncthreads();
    int nd = (b << BSHIFT) + t;
    if (t < BSIZE && nd < N_NODES) dinv[nd] = rsqrtf((float)cnt[t] + 1.0f);
}

// Pass C: per-bucket node sort into padded interleaved CSR: entry=(src,coef).
// Rows padded to multiples of 16 (dummy = own node, coef 0). 16-aligned starts.
__global__ __launch_bounds__(256) void passC_kernel(const unsigned* __restrict__ rec,
                                                    const int* __restrict__ bucket_cur,
                                                    const float* __restrict__ dinv,
                                                    int2* __restrict__ row_meta,
                                                    int2* __restrict__ csr) {
    __shared__ unsigned stage[CAPB];
    __shared__ int cnt[BSIZE];
    __shared__ int pds[BSIZE];
    __shared__ int cur[BSIZE];
    __shared__ float sdv[BSIZE];
    int t = threadIdx.x, b = blockIdx.x;
    int node0 = b << BSHIFT;
    int e0 = b * CAPB;
    int n = bucket_cur[b * CURSTR] - e0;
    int pbase = b * CSTRIDE;              // mult of 16
    if (t < BSIZE) {
        cnt[t] = 0;
        int nd = node0 + t;
        sdv[t] = (nd < N_NODES) ? dinv[nd] : 0.f;
    }
    __syncthreads();
    for (int k = t; k < n; k += 256) {
        unsigned r = rec[e0 + k];
        stage[k] = r;
        atomicAdd(&cnt[r >> 20], 1);
    }
    __syncthreads();
    int pd = 0;
    if (t < BSIZE) { pd = (cnt[t] + 15) & ~15; pds[t] = pd; }
    __syncthreads();
    for (int off = 1; off < BSIZE; off <<= 1) {
        int v = (t < BSIZE && t >= off) ? pds[t - off] : 0;
        __syncthreads();
        if (t < BSIZE) pds[t] += v;
        __syncthreads();
    }
    if (t < BSIZE) {
        int startp = pbase + pds[t] - pd;
        cur[t] = startp;
        int nd = node0 + t;
        if (nd < N_NODES) {
            row_meta[nd] = make_int2(startp, pd);
            for (int k = startp + cnt[t]; k < startp + pd; ++k)
                csr[k] = make_int2(nd, 0);   // dummy: own node, coef 0
        }
    }
    __syncthreads();
    for (int k = t; k < n; k += 256) {
        unsigned r = stage[k];
        int dl = r >> 20;
        int s  = r & 0xFFFFF;
        int pos = atomicAdd(&cur[dl], 1);
        csr[pos] = make_int2(s, __float_as_int(dinv[s] * sdv[dl]));
    }
}

// ---------------------------------------------------------------------------
// Layer 0: f32 x rows (64B), 16 lanes/row, 16-edge chunks; writes fp8 h.
__global__ __launch_bounds__(256) void layer0_kernel(
        const float* __restrict__ xf,
        const int2* __restrict__ row_meta,
        const v4i* __restrict__ csr4,
        const float* __restrict__ dinv,
        const float* __restrict__ W,       // [16][32]
        const float* __restrict__ bias,
        unsigned short* __restrict__ out8) {
    __shared__ float sW[F_IN * H_DIM];
    __shared__ float sb[H_DIM];
    __shared__ float agg[NPB0][F_IN + 1];
    int t = threadIdx.x;
    for (int k = t; k < F_IN * H_DIM; k += 256) sW[k] = W[k];
    if (t < H_DIM) sb[t] = bias[t];

    int nl = t >> 4, ln = t & 15;
    int i = blockIdx.x * NPB0 + nl;
    int2 m = row_meta[i];
    float di = dinv[i], di2 = di * di;
    int q    = m.x >> 1;
    int qend = (m.x + m.y) >> 1;

    float acc = xf[i * F_IN + ln] * di2;
    for (; q + 8 <= qend; q += 8) {
        v4i ca[8];
#pragma unroll
        for (int k = 0; k < 8; ++k) ca[k] = __builtin_nontemporal_load(&csr4[q + k]);
        float v[16];
#pragma unroll
        for (int k = 0; k < 8; ++k) {
            v[2 * k]     = xf[ca[k].x * F_IN + ln];
            v[2 * k + 1] = xf[ca[k].z * F_IN + ln];
        }
#pragma unroll
        for (int k = 0; k < 8; ++k)
            acc += v[2 * k] * __int_as_float(ca[k].y)
                 + v[2 * k + 1] * __int_as_float(ca[k].w);
    }
    agg[nl][ln] = acc;
    __syncthreads();

    int j0 = 2 * ln;
    float o0 = sb[j0], o1 = sb[j0 + 1];
    const float* arow = &agg[nl][0];
#pragma unroll
    for (int k = 0; k < F_IN; ++k) {
        float a = arow[k];
        o0 += a * sW[k * H_DIM + j0];
        o1 += a * sW[k * H_DIM + j0 + 1];
    }
    out8[i * 16 + ln] = f32x2_to_fp8x2(tanhf(o0), tanhf(o1));
}

// ---------------------------------------------------------------------------
// fp8 layers: 8 lanes/row (rows are 8 dwords of fp8x4). One gather serves 8
// rows; one per-lane v4i CSR load carries a 16-edge chunk (2 edges/lane,
// broadcast via shfl width 8). Rows padded to 16 edges => no tails.
template <bool FINAL>
__global__ __launch_bounds__(256) void layer8_kernel(
        const unsigned* __restrict__ hp32,   // fp8x4 dwords, 8/row
        const int2* __restrict__ row_meta,
        const v4i* __restrict__ csr4,
        const float* __restrict__ dinv,
        const float* __restrict__ W,         // [32][32]
        const float* __restrict__ bias,
        unsigned* __restrict__ out32,        // fp8x4 dwords (non-final)
        unsigned* __restrict__ outbf) {      // bf16x2 pairs (final)
    __shared__ float sW[H_DIM * H_DIM];
    __shared__ float sb[H_DIM];
    __shared__ float agg[NPB8][H_DIM + 1];
    int t = threadIdx.x;
    for (int k = t; k < H_DIM * H_DIM; k += 256) sW[k] = W[k];
    if (t < H_DIM) sb[t] = bias[t];

    int nl = t >> 3, ln = t & 7;
    int i = blockIdx.x * NPB8 + nl;
    int2 m = row_meta[i];
    float di = dinv[i], di2 = di * di;

    unsigned su = hp32[i * 8 + ln];
    v2f slo = fp8pk<false>(su), shi = fp8pk<true>(su);
    float a0 = slo.x * di2, a1 = slo.y * di2, a2 = shi.x * di2, a3 = shi.y * di2;

    int q4 = m.x >> 1;                 // v4i base index (m.x mult of 16)
    int nch = m.y >> 4;                // 16-edge chunks
    for (int c = 0; c < nch; ++c) {
        v4i ca = __builtin_nontemporal_load(&csr4[q4 + c * 8 + ln]);
        unsigned v[16]; float cf[16];
#pragma unroll
        for (int k = 0; k < 16; ++k) {
            int sk = __shfl((k & 1) ? ca.z : ca.x, k >> 1, 8);
            cf[k]  = __int_as_float(__shfl((k & 1) ? ca.w : ca.y, k >> 1, 8));
            v[k] = hp32[sk * 8 + ln];
        }
#pragma unroll
        for (int k = 0; k < 16; ++k) {
            v2f lo = fp8pk<false>(v[k]), hi = fp8pk<true>(v[k]);
            a0 += lo.x * cf[k]; a1 += lo.y * cf[k];
            a2 += hi.x * cf[k]; a3 += hi.y * cf[k];
        }
    }
    agg[nl][4 * ln]     = a0;
    agg[nl][4 * ln + 1] = a1;
    agg[nl][4 * ln + 2] = a2;
    agg[nl][4 * ln + 3] = a3;
    __syncthreads();

    // transform: 32 nodes x 8 lanes, 4 output feats per thread
    int j0 = 4 * ln;
    float o0 = sb[j0], o1 = sb[j0 + 1], o2 = sb[j0 + 2], o3 = sb[j0 + 3];
    const float* arow = &agg[nl][0];
#pragma unroll
    for (int k = 0; k < H_DIM; ++k) {
        float a = arow[k];
        o0 += a * sW[k * H_DIM + j0];
        o1 += a * sW[k * H_DIM + j0 + 1];
        o2 += a * sW[k * H_DIM + j0 + 2];
        o3 += a * sW[k * H_DIM + j0 + 3];
    }
    o0 = tanhf(o0); o1 = tanhf(o1); o2 = tanhf(o2); o3 = tanhf(o3);
    if (!FINAL) {
        out32[i * 8 + ln] = (unsigned)f32x2_to_fp8x2(o0, o1)
                          | ((unsigned)f32x2_to_fp8x2(o2, o3) << 16);
    } else {
        outbf[i * 16 + 2 * ln]     = pack_bf16x2(o0, o1);
        outbf[i * 16 + 2 * ln + 1] = pack_bf16x2(o2, o3);
    }
}

// ---------------------------------------------------------------------------
// Per-graph pooling (batch sorted) + linear head, reading packed bf16 h.
__global__ __launch_bounds__(256) void pool_kernel(const unsigned* __restrict__ hp,
                                                   const int* __restrict__ batch,
                                                   const float* __restrict__ Wout,
                                                   const float* __restrict__ bout,
                                                   float* __restrict__ out) {
    int b = blockIdx.x;
    int t = threadIdx.x;
    int lane_n = t >> 5;
    int j = t & 31;

    int lo = 0, hi = N_NODES;
    while (lo < hi) { int mid = (lo + hi) >> 1; if (batch[mid] < b) lo = mid + 1; else hi = mid; }
    int start = lo;
    hi = N_NODES;
    while (lo < hi) { int mid = (lo + hi) >> 1; if (batch[mid] < b + 1) lo = mid + 1; else hi = mid; }
    int end = lo;

    float vmax = -INFINITY, vsum = 0.f;
    for (int i = start + lane_n; i < end; i += 8) {
        unsigned q = hp[i * 16 + (j >> 1)];
        float v = (j & 1) ? bf_hi(q) : bf_lo(q);
        vmax = fmaxf(vmax, v);
        vsum += v;
    }

    __shared__ float smax[8][32];
    __shared__ float ssum[8][32];
    __shared__ float pool96[96];
    smax[lane_n][j] = vmax;
    ssum[lane_n][j] = vsum;
    __syncthreads();

    if (t < 32) {
        float m = smax[0][t], s = ssum[0][t];
#pragma unroll
        for (int n = 1; n < 8; ++n) { m = fmaxf(m, smax[n][t]); s += ssum[n][t]; }
        int cnt = end - start;
        float mean = s / fmaxf((float)cnt, 1.0f);
        pool96[t]      = m;
        pool96[32 + t] = mean;
        pool96[64 + t] = s;
    }
    __syncthreads();

    if (t < 96) out[B_GRAPHS + b * 96 + t] = pool96[t];

    __shared__ float dotbuf[96];
    if (t < 96) dotbuf[t] = pool96[t] * Wout[t];
    __syncthreads();
    if (t == 0) {
        float acc = 0.f;
#pragma unroll
        for (int k = 0; k < 96; ++k) acc += dotbuf[k];
        out[b] = acc + bout[0];
    }
}

// ---------------------------------------------------------------------------
extern "C" void kernel_launch(void* const* d_in, const int* in_sizes, int n_in,
                              void* d_out, int out_size, void* d_ws, size_t ws_size,
                              hipStream_t stream) {
    const float* x     = (const float*)d_in[0];
    const int*   ei    = (const int*)  d_in[1];
    const int*   batch = (const int*)  d_in[2];
    const float* W0    = (const float*)d_in[3];
    const float* b0    = (const float*)d_in[4];
    const float* W1    = (const float*)d_in[5];
    const float* b1    = (const float*)d_in[6];
    const float* W2    = (const float*)d_in[7];
    const float* b2    = (const float*)d_in[8];
    const float* W3    = (const float*)d_in[9];
    const float* b3    = (const float*)d_in[10];
    const float* Wout  = (const float*)d_in[11];
    const float* bout  = (const float*)d_in[12];
    float* out = (float*)d_out;

    char* p = (char*)d_ws;
    float*          dinv       = (float*)p;          p += (size_t)N_NODES * 4;
    unsigned short* h8A        = (unsigned short*)p; p += (size_t)N_NODES * 16 * 2;   // 3.2 MB
    unsigned short* h8B        = (unsigned short*)p; p += (size_t)N_NODES * 16 * 2;   // 3.2 MB
    unsigned*       rec        = (unsigned*)p;       p += (size_t)NBUCKET * CAPB * 4; // 8 MB
    int2*           csr        = (int2*)p;           p += (size_t)TPAD * 8;           // 22.4 MB
    int2*           row_meta   = (int2*)p;           p += (size_t)N_NODES * 8;
    int*            bucket_cur = (int*)p;            p += (size_t)NBUCKET * CURSTR * 4;
    unsigned* hBF = rec;   // alias: rec dead after passC (bf16 h for pooling)

    // ---- edge build ----
    init_cur_kernel<<<(NBUCKET + 255) / 256, 256, 0, stream>>>(bucket_cur);
    passB_kernel<<<NCHUNK, 1024, 0, stream>>>(ei, bucket_cur, rec);
    dinv_kernel<<<NBUCKET, 256, 0, stream>>>(rec, bucket_cur, dinv);
    passC_kernel<<<NBUCKET, 256, 0, stream>>>(rec, bucket_cur, dinv, row_meta, csr);

    // ---- layers: layer0 (f32 in, 16-lane) then 3x fp8 8-lane layers ----
    layer0_kernel<<<L0_BLOCKS, 256, 0, stream>>>(
        x, row_meta, (const v4i*)csr, dinv, W0, b0, h8A);
    layer8_kernel<false><<<L8_BLOCKS, 256, 0, stream>>>(
        (const unsigned*)h8A, row_meta, (const v4i*)csr, dinv, W1, b1,
        (unsigned*)h8B, (unsigned*)nullptr);
    layer8_kernel<false><<<L8_BLOCKS, 256, 0, stream>>>(
        (const unsigned*)h8B, row_meta, (const v4i*)csr, dinv, W2, b2,
        (unsigned*)h8A, (unsigned*)nullptr);
    layer8_kernel<true><<<L8_BLOCKS, 256, 0, stream>>>(
        (const unsigned*)h8A, row_meta, (const v4i*)csr, dinv, W3, b3,
        (unsigned*)nullptr, hBF);

    pool_kernel<<<B_GRAPHS, 256, 0, stream>>>(hBF, batch, Wout, bout, out);
}